// Round 1
// baseline (4556.389 us; speedup 1.0000x reference)
//
#include <hip/hip_runtime.h>
#include <math.h>

#define N_CH 62
#define NB 128
#define F 32
#define TLEN 128
#define HID 512
#define G3 1536
#define EPER 992
#define NNODE (N_CH * NB)   // 7936
#define ETOT (EPER * NB)    // 126976
#define FT (F * TLEN)       // 4096
#define DIM (N_CH * F)      // 1984
#define MROWS (NB * TLEN)   // 16384

__device__ __forceinline__ float sigmoidf_(float x) { return 1.f / (1.f + __expf(-x)); }

__device__ __forceinline__ float gru_one(float xr, float xz, float xn,
                                         float hr, float hz, float hn, float h) {
  float r = sigmoidf_(xr + hr);
  float z = sigmoidf_(xz + hz);
  float n = tanhf(xn + r * hn);
  return (1.f - z) * n + z * h;
}

// ---------------- graph preprocessing ----------------
__global__ void k_deg(const int* __restrict__ src, const float* __restrict__ w,
                      float* __restrict__ deg) {
  int e = blockIdx.x * 256 + threadIdx.x;
  if (e < ETOT) atomicAdd(&deg[src[e]], w[e]);
}

__global__ void k_wn(const int* __restrict__ src, const int* __restrict__ dst,
                     const float* __restrict__ w, const float* __restrict__ deg,
                     float* __restrict__ wn) {
  int e = blockIdx.x * 256 + threadIdx.x;
  if (e < ETOT) {
    float ds = deg[src[e]], dd = deg[dst[e]];
    float a = ds > 0.f ? rsqrtf(ds) : 0.f;
    float b = dd > 0.f ? rsqrtf(dd) : 0.f;
    wn[e] = -a * w[e] * b;
  }
}

// Build CSR adjacency (by dst) for the prototype graph (first EPER edges, nodes 0..61).
__global__ void k_adj(const int* __restrict__ src, const int* __restrict__ dst,
                      int* __restrict__ adj_start, int* __restrict__ adj_src,
                      int* __restrict__ adj_j) {
  __shared__ int cnt[N_CH];
  __shared__ int start[N_CH + 1];
  __shared__ int pos[N_CH];
  int tid = threadIdx.x;
  if (tid < N_CH) { cnt[tid] = 0; pos[tid] = 0; }
  __syncthreads();
  for (int j = tid; j < EPER; j += blockDim.x) atomicAdd(&cnt[dst[j]], 1);
  __syncthreads();
  if (tid == 0) {
    int r = 0;
    for (int c = 0; c < N_CH; c++) { start[c] = r; r += cnt[c]; }
    start[N_CH] = r;
  }
  __syncthreads();
  for (int j = tid; j < EPER; j += blockDim.x) {
    int c = dst[j];
    int slot = start[c] + atomicAdd(&pos[c], 1);
    adj_src[slot] = src[j];
    adj_j[slot] = j;
  }
  if (tid <= N_CH) adj_start[tid] = start[tid];
}

// out[n] = sum_{in-edges e of n} wn[e] * in[src(e)]   (per-node [F,T] block)
__global__ __launch_bounds__(256) void k_prop(const float* __restrict__ in,
                                              float* __restrict__ out,
                                              const float* __restrict__ wn,
                                              const int* __restrict__ adj_start,
                                              const int* __restrict__ adj_src,
                                              const int* __restrict__ adj_j) {
  int n = blockIdx.x, b = n / N_CH, c = n % N_CH;
  int tid = threadIdx.x;
  __shared__ int s_src[EPER];
  __shared__ float s_w[EPER];
  int a0 = adj_start[c], d = adj_start[c + 1] - a0;
  for (int i = tid; i < d; i += 256) {
    s_src[i] = adj_src[a0 + i];
    s_w[i] = wn[b * EPER + adj_j[a0 + i]];
  }
  __syncthreads();
  const float* inb = in + (size_t)b * N_CH * FT;
  float4 acc[4];
#pragma unroll
  for (int i = 0; i < 4; i++) acc[i] = make_float4(0.f, 0.f, 0.f, 0.f);
  int e0 = tid * 16;
  for (int q = 0; q < d; q++) {
    const float* p = inb + (size_t)s_src[q] * FT + e0;
    float w = s_w[q];
#pragma unroll
    for (int i = 0; i < 4; i++) {
      float4 v = *(const float4*)&p[i * 4];
      acc[i].x += w * v.x; acc[i].y += w * v.y; acc[i].z += w * v.z; acc[i].w += w * v.w;
    }
  }
  float* ob = out + (size_t)n * FT + e0;
#pragma unroll
  for (int i = 0; i < 4; i++) *(float4*)&ob[i * 4] = acc[i];
}

// Fused: Tx2 = 2*prop(Tx1) - Tx0;  out = Tx0*W0 + Tx1*W1 + Tx2*W2 + b  (+lrelu / seq-write)
template <int LAYER>
__global__ __launch_bounds__(256) void k_combine(const float* __restrict__ t0src,
                                                 const float* __restrict__ t1src,
                                                 const float* __restrict__ W,
                                                 const float* __restrict__ bias,
                                                 const float* __restrict__ wn,
                                                 const int* __restrict__ adj_start,
                                                 const int* __restrict__ adj_src,
                                                 const int* __restrict__ adj_j,
                                                 float* __restrict__ out) {
  int n = blockIdx.x, b = n / N_CH, c = n % N_CH;
  int tid = threadIdx.x;
  __shared__ __align__(16) float s0[FT];
  __shared__ __align__(16) float s1[FT];
  __shared__ __align__(16) float s2[FT];
  __shared__ __align__(16) float sWt[3 * 1152];  // [a][g*36 + f], padded
  __shared__ float sb[F];
  __shared__ int s_src[EPER];
  __shared__ float s_w[EPER];

  int a0 = adj_start[c], d = adj_start[c + 1] - a0;
  for (int i = tid; i < d; i += 256) {
    s_src[i] = adj_src[a0 + i];
    s_w[i] = wn[b * EPER + adj_j[a0 + i]];
  }
  for (int i = tid; i < 3 * F * F; i += 256) {
    int a = i >> 10, r = i & 1023, g = r >> 5, f = r & 31;
    sWt[a * 1152 + g * 36 + f] = W[(a << 10) + (f << 5) + g];
  }
  if (tid < F) sb[tid] = bias[tid];

  int e0 = tid * 16;
  float4 a4[4];
  {
    const float* t0n = t0src + (size_t)n * FT + e0;
    const float* t1n = t1src + (size_t)n * FT + e0;
#pragma unroll
    for (int i = 0; i < 4; i++) {
      a4[i] = *(const float4*)&t0n[i * 4];
      *(float4*)&s0[e0 + i * 4] = a4[i];
      *(float4*)&s1[e0 + i * 4] = *(const float4*)&t1n[i * 4];
    }
  }
  __syncthreads();
  {
    const float* t1b = t1src + (size_t)b * N_CH * FT;
    float4 acc[4];
#pragma unroll
    for (int i = 0; i < 4; i++) acc[i] = make_float4(0.f, 0.f, 0.f, 0.f);
    for (int q = 0; q < d; q++) {
      const float* p = t1b + (size_t)s_src[q] * FT + e0;
      float w = s_w[q];
#pragma unroll
      for (int i = 0; i < 4; i++) {
        float4 v = *(const float4*)&p[i * 4];
        acc[i].x += w * v.x; acc[i].y += w * v.y; acc[i].z += w * v.z; acc[i].w += w * v.w;
      }
    }
#pragma unroll
    for (int i = 0; i < 4; i++) {
      float4 s;
      s.x = 2.f * acc[i].x - a4[i].x;
      s.y = 2.f * acc[i].y - a4[i].y;
      s.z = 2.f * acc[i].z - a4[i].z;
      s.w = 2.f * acc[i].w - a4[i].w;
      *(float4*)&s2[e0 + i * 4] = s;
    }
  }
  __syncthreads();

  // compute: thread owns 4 g x 4 t
  int gq = tid >> 5, tq = tid & 31;
  int g0 = gq << 2, t0 = tq << 2;
  float acc[4][4];
#pragma unroll
  for (int i = 0; i < 4; i++)
#pragma unroll
    for (int j = 0; j < 4; j++) acc[i][j] = 0.f;

#pragma unroll
  for (int f0 = 0; f0 < 32; f0 += 4) {
    float4 w0v[4], w1v[4], w2v[4];
#pragma unroll
    for (int gi = 0; gi < 4; gi++) {
      w0v[gi] = *(const float4*)&sWt[0 * 1152 + (g0 + gi) * 36 + f0];
      w1v[gi] = *(const float4*)&sWt[1 * 1152 + (g0 + gi) * 36 + f0];
      w2v[gi] = *(const float4*)&sWt[2 * 1152 + (g0 + gi) * 36 + f0];
    }
#pragma unroll
    for (int ff = 0; ff < 4; ff++) {
      float4 v0 = *(const float4*)&s0[(f0 + ff) * 128 + t0];
      float4 v1 = *(const float4*)&s1[(f0 + ff) * 128 + t0];
      float4 v2 = *(const float4*)&s2[(f0 + ff) * 128 + t0];
#pragma unroll
      for (int gi = 0; gi < 4; gi++) {
        float w0 = ((const float*)&w0v[gi])[ff];
        float w1 = ((const float*)&w1v[gi])[ff];
        float w2 = ((const float*)&w2v[gi])[ff];
        acc[gi][0] += v0.x * w0 + v1.x * w1 + v2.x * w2;
        acc[gi][1] += v0.y * w0 + v1.y * w1 + v2.y * w2;
        acc[gi][2] += v0.z * w0 + v1.z * w1 + v2.z * w2;
        acc[gi][3] += v0.w * w0 + v1.w * w1 + v2.w * w2;
      }
    }
  }

  if (LAYER == 1) {
#pragma unroll
    for (int gi = 0; gi < 4; gi++) {
      float bb = sb[g0 + gi];
      float4 o;
      o.x = acc[gi][0] + bb; o.x = o.x > 0.f ? o.x : 0.01f * o.x;
      o.y = acc[gi][1] + bb; o.y = o.y > 0.f ? o.y : 0.01f * o.y;
      o.z = acc[gi][2] + bb; o.z = o.z > 0.f ? o.z : 0.01f * o.z;
      o.w = acc[gi][3] + bb; o.w = o.w > 0.f ? o.w : 0.01f * o.w;
      *(float4*)&out[(size_t)n * FT + (g0 + gi) * 128 + t0] = o;
    }
  } else {
#pragma unroll
    for (int tt = 0; tt < 4; tt++) {
      float4 o;
      o.x = acc[0][tt] + sb[g0 + 0];
      o.y = acc[1][tt] + sb[g0 + 1];
      o.z = acc[2][tt] + sb[g0 + 2];
      o.w = acc[3][tt] + sb[g0 + 3];
      *(float4*)&out[((size_t)(b * TLEN + t0 + tt)) * DIM + c * F + g0] = o;
    }
  }
}

// ---------------- big input-gate GEMM: xg[m,n] = sum_k seq[m,k]*W_ih[n,k] + b_ih[n] --------
__global__ __launch_bounds__(256) void k_gemm_xg(const float* __restrict__ Amat,
                                                 const float* __restrict__ Bmat,
                                                 const float* __restrict__ bias,
                                                 float* __restrict__ Cmat) {
  __shared__ __align__(16) float As[16][132];
  __shared__ __align__(16) float Bs[16][132];
  int tid = threadIdx.x;
  int m0 = blockIdx.x * 128, n0 = blockIdx.y * 128;
  int tm = tid & 15, tn = tid >> 4;
  float acc[8][8];
#pragma unroll
  for (int i = 0; i < 8; i++)
#pragma unroll
    for (int j = 0; j < 8; j++) acc[i][j] = 0.f;

  for (int k0 = 0; k0 < DIM; k0 += 16) {
#pragma unroll
    for (int h = 0; h < 2; h++) {
      int p = tid + h * 256;
      int mm = p >> 2, kq = p & 3;
      float4 va = *(const float4*)&Amat[(size_t)(m0 + mm) * DIM + k0 + kq * 4];
      As[kq * 4 + 0][mm] = va.x; As[kq * 4 + 1][mm] = va.y;
      As[kq * 4 + 2][mm] = va.z; As[kq * 4 + 3][mm] = va.w;
      float4 vb = *(const float4*)&Bmat[(size_t)(n0 + mm) * DIM + k0 + kq * 4];
      Bs[kq * 4 + 0][mm] = vb.x; Bs[kq * 4 + 1][mm] = vb.y;
      Bs[kq * 4 + 2][mm] = vb.z; Bs[kq * 4 + 3][mm] = vb.w;
    }
    __syncthreads();
#pragma unroll
    for (int kk = 0; kk < 16; kk++) {
      float a[8], b[8];
      *(float4*)&a[0] = *(const float4*)&As[kk][tm * 8];
      *(float4*)&a[4] = *(const float4*)&As[kk][tm * 8 + 4];
      *(float4*)&b[0] = *(const float4*)&Bs[kk][tn * 8];
      *(float4*)&b[4] = *(const float4*)&Bs[kk][tn * 8 + 4];
#pragma unroll
      for (int i = 0; i < 8; i++)
#pragma unroll
        for (int j = 0; j < 8; j++) acc[i][j] += a[i] * b[j];
    }
    __syncthreads();
  }

  float bv[8];
  *(float4*)&bv[0] = *(const float4*)&bias[n0 + tn * 8];
  *(float4*)&bv[4] = *(const float4*)&bias[n0 + tn * 8 + 4];
#pragma unroll
  for (int i = 0; i < 8; i++) {
    size_t row = (size_t)(m0 + tm * 8 + i) * G3 + n0 + tn * 8;
    float4 o0 = make_float4(acc[i][0] + bv[0], acc[i][1] + bv[1], acc[i][2] + bv[2], acc[i][3] + bv[3]);
    float4 o1 = make_float4(acc[i][4] + bv[4], acc[i][5] + bv[5], acc[i][6] + bv[6], acc[i][7] + bv[7]);
    *(float4*)&Cmat[row] = o0;
    *(float4*)&Cmat[row + 4] = o1;
  }
}

__global__ void k_transpose_whh(const float* __restrict__ W, float* __restrict__ Wt) {
  int idx = blockIdx.x * 256 + threadIdx.x;
  if (idx < HID * G3) {
    int g = idx / HID, k = idx % HID;   // coalesced read of W[g][k]
    Wt[(size_t)k * G3 + g] = W[idx];
  }
}

// one GRU time step; h staged in LDS, k-split 4-way with shfl reduce
#define REDC(v) { v += __shfl_xor(v, 8); v += __shfl_xor(v, 16); }
__global__ __launch_bounds__(256) void k_gru_step(const float* __restrict__ xg,
                                                  const float* __restrict__ Wt,
                                                  const float* __restrict__ bhh,
                                                  const float* __restrict__ hin,
                                                  float* __restrict__ hout, int t) {
  __shared__ __align__(16) float sh[8 * 528];  // 8 b x 512, ks-padded
  int tid = threadIdx.x;
  int jt = blockIdx.x & 15;   // 16 j-tiles of 32
  int bt = blockIdx.x >> 4;   // 16 b-tiles of 8
  int b_l = tid >> 5;         // 0..7
  int ks = (tid >> 3) & 3;    // 0..3 (intra-wave)
  int jg = tid & 7;           // 0..7
  int j = jt * 32 + jg * 4;
  int b = bt * 8 + b_l;

  for (int i = tid; i < 8 * HID; i += 256) {
    int bl = i >> 9, kk = i & 511;
    sh[bl * 528 + kk + ((kk >> 7) << 2)] = hin[(size_t)bt * 8 * HID + i];
  }
  __syncthreads();

  float4 ar = make_float4(0.f, 0.f, 0.f, 0.f);
  float4 az = make_float4(0.f, 0.f, 0.f, 0.f);
  float4 an = make_float4(0.f, 0.f, 0.f, 0.f);
  const float* wp = Wt + (size_t)(ks * 128) * G3;
  const float* shp = sh + b_l * 528 + ks * 132;
#pragma unroll 4
  for (int k = 0; k < 128; k++) {
    float hk = shp[k];
    float4 wr = *(const float4*)&wp[(size_t)k * G3 + j];
    float4 wz = *(const float4*)&wp[(size_t)k * G3 + 512 + j];
    float4 wv = *(const float4*)&wp[(size_t)k * G3 + 1024 + j];
    ar.x += hk * wr.x; ar.y += hk * wr.y; ar.z += hk * wr.z; ar.w += hk * wr.w;
    az.x += hk * wz.x; az.y += hk * wz.y; az.z += hk * wz.z; az.w += hk * wz.w;
    an.x += hk * wv.x; an.y += hk * wv.y; an.z += hk * wv.z; an.w += hk * wv.w;
  }
  REDC(ar.x) REDC(ar.y) REDC(ar.z) REDC(ar.w)
  REDC(az.x) REDC(az.y) REDC(az.z) REDC(az.w)
  REDC(an.x) REDC(an.y) REDC(an.z) REDC(an.w)

  if (ks == 0) {
    float4 brv = *(const float4*)&bhh[j];
    float4 bzv = *(const float4*)&bhh[512 + j];
    float4 bnv = *(const float4*)&bhh[1024 + j];
    size_t mrow = ((size_t)b * TLEN + t) * G3;
    float4 xr = *(const float4*)&xg[mrow + j];
    float4 xz = *(const float4*)&xg[mrow + 512 + j];
    float4 xn = *(const float4*)&xg[mrow + 1024 + j];
    float4 hold = *(const float4*)&sh[b_l * 528 + j + ((j >> 7) << 2)];
    float4 o;
    o.x = gru_one(xr.x, xz.x, xn.x, ar.x + brv.x, az.x + bzv.x, an.x + bnv.x, hold.x);
    o.y = gru_one(xr.y, xz.y, xn.y, ar.y + brv.y, az.y + bzv.y, an.y + bnv.y, hold.y);
    o.z = gru_one(xr.z, xz.z, xn.z, ar.z + brv.z, az.z + bzv.z, an.z + bnv.z, hold.z);
    o.w = gru_one(xr.w, xz.w, xn.w, ar.w + brv.w, az.w + bnv.w * 0.f + bzv.w * 0.f + (az.w + bzv.w) * 0.f + bzv.w, an.w + bnv.w, hold.w);
    // NOTE: line above must be exactly az.w + bzv.w; write it plainly:
    o.w = gru_one(xr.w, xz.w, xn.w, ar.w + brv.w, az.w + bzv.w, an.w + bnv.w, hold.w);
    *(float4*)&hout[(size_t)b * HID + j] = o;
  }
}

__global__ void k_final(const float* __restrict__ h, const float* __restrict__ Wlin,
                        const float* __restrict__ blin, float* __restrict__ out) {
  int b = blockIdx.x;
  int tid = threadIdx.x;
  int o = tid >> 6, lane = tid & 63;
  float acc = 0.f;
  for (int k = lane; k < HID; k += 64) acc += h[(size_t)b * HID + k] * Wlin[o * HID + k];
#pragma unroll
  for (int off = 32; off; off >>= 1) acc += __shfl_down(acc, off);
  if (lane == 0) out[b * 4 + o] = acc + blin[o];
}

extern "C" void kernel_launch(void* const* d_in, const int* in_sizes, int n_in,
                              void* d_out, int out_size, void* d_ws, size_t ws_size,
                              hipStream_t stream) {
  const float* x = (const float*)d_in[0];
  const int* eidx = (const int*)d_in[1];
  const float* ew = (const float*)d_in[2];
  const float* Wc1 = (const float*)d_in[4];
  const float* bc1 = (const float*)d_in[5];
  const float* Wc2 = (const float*)d_in[6];
  const float* bc2 = (const float*)d_in[7];
  const float* Wih = (const float*)d_in[8];
  const float* Whh = (const float*)d_in[9];
  const float* bih = (const float*)d_in[10];
  const float* bhh = (const float*)d_in[11];
  const float* Wlin = (const float*)d_in[12];
  const float* blin = (const float*)d_in[13];
  const int* src = eidx;
  const int* dst = eidx + ETOT;

  const size_t BIGF = (size_t)NNODE * FT;           // 32,505,856 floats
  const size_t BIGB = BIGF * 4;                     // 130,023,424 bytes
  char* ws = (char*)d_ws;
  float* A = (float*)ws;                            // Tx1 / Ty1, then xg
  float* C = (float*)(ws + BIGB);                   // h1
  float* D = (float*)(ws + 2 * BIGB);               // seq [B,T,DIM]
  char* S = ws + 3 * BIGB;
  float* deg = (float*)S;                           // 32768 B
  float* wn = (float*)(S + 32768);                  // 507904 B
  int* adj_src = (int*)(S + 540672);
  int* adj_j = (int*)(S + 544768);
  int* adj_start = (int*)(S + 548864);
  float* Wt = (float*)(S + 549376);                 // 3,145,728 B
  float* h0 = (float*)(S + 3695104);                // 262144 B
  float* h1 = (float*)(S + 3957248);                // 262144 B
  float* xg = A;

  if (ws_size < 3 * BIGB + 4219392) return;  // insufficient scratch: fail cleanly

  hipMemsetAsync(deg, 0, 32768, stream);
  hipMemsetAsync(h0, 0, 262144, stream);

  k_deg<<<ETOT / 256, 256, 0, stream>>>(src, ew, deg);
  k_wn<<<ETOT / 256, 256, 0, stream>>>(src, dst, ew, deg, wn);
  k_adj<<<1, 256, 0, stream>>>(src, dst, adj_start, adj_src, adj_j);

  // ChebConv layer 1
  k_prop<<<NNODE, 256, 0, stream>>>(x, A, wn, adj_start, adj_src, adj_j);
  k_combine<1><<<NNODE, 256, 0, stream>>>(x, A, Wc1, bc1, wn, adj_start, adj_src, adj_j, C);
  // ChebConv layer 2 (writes seq layout [B,T,DIM])
  k_prop<<<NNODE, 256, 0, stream>>>(C, A, wn, adj_start, adj_src, adj_j);
  k_combine<2><<<NNODE, 256, 0, stream>>>(C, A, Wc2, bc2, wn, adj_start, adj_src, adj_j, D);

  k_transpose_whh<<<(HID * G3) / 256, 256, 0, stream>>>(Whh, Wt);

  dim3 gg(MROWS / 128, G3 / 128);
  k_gemm_xg<<<gg, 256, 0, stream>>>(D, Wih, bih, xg);

  for (int t = 0; t < TLEN; t++) {
    const float* hin = (t & 1) ? h1 : h0;
    float* hout = (t & 1) ? h0 : h1;
    k_gru_step<<<256, 256, 0, stream>>>(xg, Wt, bhh, hin, hout, t);
  }
  // after t=127 (odd) the result is in h0
  k_final<<<NB, 256, 0, stream>>>(h0, Wlin, blin, (float*)d_out);
}